// Round 13
// baseline (274.042 us; speedup 1.0000x reference)
//
#include <hip/hip_runtime.h>

typedef unsigned short ushort_t;
typedef unsigned int uint_t;

#define L_TOK 3072
#define DMODEL 512
#define WELEM 262144   // 512*512

using bf16x8 = __attribute__((ext_vector_type(8))) short;
using f32x4  = __attribute__((ext_vector_type(4))) float;

__device__ __forceinline__ float b2f(ushort_t u) {
    union { uint_t i; float f; } c; c.i = ((uint_t)u) << 16; return c.f;
}
__device__ __forceinline__ ushort_t f2b(float f) {
    union { float f; uint_t i; } c; c.f = f;
    uint_t x = c.i;
    return (ushort_t)((x + 0x7fffu + ((x >> 16) & 1u)) >> 16);  // RNE
}

// ---------------- Fused prologue: blocks [0,1536) convert weights, [1536,7680) embed,
// block 7680 computes start[] scan.
__global__ __launch_bounds__(256) void prologue_kernel(
    const float* __restrict__ Wq, const float* __restrict__ Wk, const float* __restrict__ Wv,
    const float* __restrict__ Wo, const float* __restrict__ W1, const float* __restrict__ W2,
    ushort_t* __restrict__ WB,
    const int* __restrict__ idx,
    const float* __restrict__ Wt, const float* __restrict__ bt,
    const float* __restrict__ Wa, const float* __restrict__ ba,
    const float* __restrict__ Wm, const float* __restrict__ bm,
    const float* __restrict__ sos, ushort_t* __restrict__ X,
    const int* __restrict__ seq, int* __restrict__ start)
{
    __shared__ int sbuf0[256];
    __shared__ int sbuf1[256];
    int bid = blockIdx.x;
    int tid = threadIdx.x;

    if (bid < 1536) {
        int gid = bid * 256 + tid;
        int mat = gid >> 16;
        int off = (gid & 65535) * 4;
        const float* src;
        switch (mat) {
            case 0: src = Wq; break;
            case 1: src = Wk; break;
            case 2: src = Wv; break;
            case 3: src = Wo; break;
            case 4: src = W1; break;
            default: src = W2; break;
        }
        float4 v = *reinterpret_cast<const float4*>(src + off);
        uint2 o;
        o.x = (uint_t)f2b(v.x) | ((uint_t)f2b(v.y) << 16);
        o.y = (uint_t)f2b(v.z) | ((uint_t)f2b(v.w) << 16);
        *reinterpret_cast<uint2*>(&WB[mat * WELEM + off]) = o;
    } else if (bid < 7680) {
        int gid = (bid - 1536) * 256 + tid;    // 3072*512 total
        int tok = gid >> 9;
        int d = gid & 511;
        float val;
        if (tok == 0) {
            val = sos[d];
        } else {
            int id = idx[tok - 1];
            int t = id / 219;            // 73*3
            int a = (id / 3) % 73;
            int m = id % 3;
            val = Wt[d * 15 + t] + bt[d]
                + Wa[d * 73 + a] + ba[d]
                + Wm[d * 3 + m] + bm[d];
        }
        X[gid] = f2b(val);
    } else {
        // start[] scan: inclusive max-scan of boundary(i) over 3072, 12 chunks of 256
        int carry = 0;
        for (int c = 0; c < 12; c++) {
            int i = c * 256 + tid;
            int b;
            if (i <= 1) b = i;
            else b = (seq[i - 1] == 0) ? i : 0;
            sbuf0[tid] = b;
            __syncthreads();
            int* src = sbuf0;
            int* dst = sbuf1;
            for (int off = 1; off < 256; off <<= 1) {
                int v = src[tid];
                if (tid >= off) { int u = src[tid - off]; if (u > v) v = u; }
                dst[tid] = v;
                __syncthreads();
                int* t = src; src = dst; dst = t;
            }
            int val = src[tid] > carry ? src[tid] : carry;
            start[i] = val;
            int tot = src[255] > carry ? src[255] : carry;
            __syncthreads();
            carry = tot;
        }
    }
}

// ---------------- GEMM: C[3072,512] = A@W^T + bias; 32x64 tile, 4 waves, double-buffered
// (R11 version, verified). TRANSV: z==2 output (V) is stored transposed VT[512][3072]
// so attention's PV B-fragments become contiguous global loads (kills the LDS transpose).
template<int RELU, int TRANSV>
__global__ __launch_bounds__(256) void gemm512(
    const ushort_t* __restrict__ A,
    const ushort_t* __restrict__ Wp0, const ushort_t* __restrict__ Wp1, const ushort_t* __restrict__ Wp2,
    const float* __restrict__ bp0, const float* __restrict__ bp1, const float* __restrict__ bp2,
    ushort_t* __restrict__ Cp0, ushort_t* __restrict__ Cp1, ushort_t* __restrict__ Cp2)
{
    const ushort_t* W = Wp0; const float* bias = bp0; ushort_t* C = Cp0;
    if (blockIdx.z == 1) { W = Wp1; bias = bp1; C = Cp1; }
    else if (blockIdx.z == 2) { W = Wp2; bias = bp2; C = Cp2; }

    __shared__ ushort_t As[2 * 32 * 72];
    __shared__ ushort_t Bs[2 * 64 * 72];

    const int tid = threadIdx.x;
    const int lane = tid & 63;
    const int w = tid >> 6;
    const int lm = lane & 15;
    const int q4 = lane >> 4;
    const int r0 = (w & 1) * 16;
    const int c0 = (w >> 1) * 32;

    const int m0 = blockIdx.x * 32;
    const int n0 = blockIdx.y * 64;

    const int srow = tid >> 3;
    const int scol = (tid & 7) << 3;
    const ushort_t* Arow = A + (size_t)(m0 + srow) * 512 + scol;
    const ushort_t* Brow0 = W + (size_t)(n0 + srow) * 512 + scol;
    const ushort_t* Brow1 = Brow0 + (size_t)32 * 512;
    const int ldsA = srow * 72 + scol;
    const int ldsB0 = srow * 72 + scol;
    const int ldsB1 = (srow + 32) * 72 + scol;

    f32x4 acc[2];
    acc[0] = (f32x4){0.f, 0.f, 0.f, 0.f};
    acc[1] = (f32x4){0.f, 0.f, 0.f, 0.f};

    uint4 a0 = *reinterpret_cast<const uint4*>(Arow);
    uint4 b0 = *reinterpret_cast<const uint4*>(Brow0);
    uint4 b1 = *reinterpret_cast<const uint4*>(Brow1);
    *reinterpret_cast<uint4*>(&As[ldsA]) = a0;
    *reinterpret_cast<uint4*>(&Bs[ldsB0]) = b0;
    *reinterpret_cast<uint4*>(&Bs[ldsB1]) = b1;
    __syncthreads();

#pragma unroll
    for (int it = 0; it < 8; it++) {
        const int curA = (it & 1) * 2304;
        const int altA = ((it & 1) ^ 1) * 2304;
        const int curB = (it & 1) * 4608;
        const int altB = ((it & 1) ^ 1) * 4608;
        const int nxt = (it + 1) * 64;

        uint4 na, nb0, nb1;
        if (it < 7) {
            na = *reinterpret_cast<const uint4*>(Arow + nxt);
            nb0 = *reinterpret_cast<const uint4*>(Brow0 + nxt);
            nb1 = *reinterpret_cast<const uint4*>(Brow1 + nxt);
        }

#pragma unroll
        for (int kk = 0; kk < 64; kk += 32) {
            bf16x8 af = *reinterpret_cast<const bf16x8*>(&As[curA + (r0 + lm) * 72 + kk + q4 * 8]);
#pragma unroll
            for (int nt = 0; nt < 2; nt++) {
                bf16x8 bf = *reinterpret_cast<const bf16x8*>(&Bs[curB + (c0 + nt * 16 + lm) * 72 + kk + q4 * 8]);
                acc[nt] = __builtin_amdgcn_mfma_f32_16x16x32_bf16(af, bf, acc[nt], 0, 0, 0);
            }
        }

        if (it < 7) {
            *reinterpret_cast<uint4*>(&As[altA + ldsA]) = na;
            *reinterpret_cast<uint4*>(&Bs[altB + ldsB0]) = nb0;
            *reinterpret_cast<uint4*>(&Bs[altB + ldsB1]) = nb1;
            __syncthreads();
        }
    }

    const bool transv = TRANSV && (blockIdx.z == 2);
#pragma unroll
    for (int nt = 0; nt < 2; nt++) {
        int col = n0 + c0 + nt * 16 + lm;
        float bv = bias[col];
#pragma unroll
        for (int r = 0; r < 4; r++) {
            int row = m0 + r0 + q4 * 4 + r;
            float v = acc[nt][r] + bv;
            if (RELU) v = (v > 0.f) ? v : 0.01f * v;
            if (transv)
                C[(size_t)col * L_TOK + row] = f2b(v);   // VT[dim][token]
            else
                C[(size_t)row * 512 + col] = f2b(v);
        }
    }
}

// ---------------- MFMA flash attention, VT edition. One wave per (16-query tile, head).
// Key set for query i: {0} ∪ [start_i, i-1]. Token 0 handled in closed form as init
// (m=s0, l=1, o=V[0] — every query attends key 0); MFMA chunks then cover the
// CONTIGUOUS range [lo, i0+15) with per-element mask sq[r] <= j < iq0+r.
// V is read as B-fragments directly from global VT[512][3072] (no LDS transpose).
__global__ __launch_bounds__(256) void attn_mfma(
    const ushort_t* __restrict__ Q, const ushort_t* __restrict__ K,
    const ushort_t* __restrict__ VT, const int* __restrict__ START,
    ushort_t* __restrict__ O)
{
    __shared__ ushort_t PsS[4][16 * 72];   // P [query][key-slot], per wave

    int w = threadIdx.x >> 6;
    int lane = threadIdx.x & 63;
    ushort_t* Ps = PsS[w];

    int gw = blockIdx.x * 4 + w;          // 1536 units
    int tile = 191 - (gw >> 3);           // reverse: long-range tiles first (LPT)
    int h = gw & 7;
    int i0 = tile * 16;
    int lm = lane & 15;
    int q4 = lane >> 4;

    int iq0 = i0 + q4 * 4;
    int sq[4];
#pragma unroll
    for (int r = 0; r < 4; r++) sq[r] = START[iq0 + r];

    int lo = START[i0]; if (lo < 1) lo = 1;
    const int kend = i0 + 15;             // tokens needed: [lo, kend) (query i needs j < i <= i0+15)

    // Q A-fragments: m=lm (query), k = q4*8 + j (dims), two halves
    const ushort_t* Qp = Q + (size_t)(i0 + lm) * 512 + h * 64 + q4 * 8;
    bf16x8 aQ0 = *reinterpret_cast<const bf16x8*>(Qp);
    bf16x8 aQ1 = *reinterpret_cast<const bf16x8*>(Qp + 32);

    // ---- token 0 in closed form: s0 = q·K0/8 per query (A-layout), redistribute to C-layout
    float s0 = 0.f;
    {
        bf16x8 k00 = *reinterpret_cast<const bf16x8*>(K + h * 64 + q4 * 8);
        bf16x8 k01 = *reinterpret_cast<const bf16x8*>(K + h * 64 + 32 + q4 * 8);
#pragma unroll
        for (int j = 0; j < 8; j++) {
            s0 += b2f((ushort_t)aQ0[j]) * b2f((ushort_t)k00[j]);
            s0 += b2f((ushort_t)aQ1[j]) * b2f((ushort_t)k01[j]);
        }
        s0 += __shfl_xor(s0, 16);
        s0 += __shfl_xor(s0, 32);
        s0 *= 0.125f;                      // lane l now holds s0 of query i0 + (l&15)
    }

    const ushort_t* VTh = VT + (size_t)h * 64 * L_TOK;
    float m_run[4], l_run[4];
    f32x4 oacc[4];
#pragma unroll
    for (int nt = 0; nt < 4; nt++) {
        float v0 = b2f(VTh[(size_t)(nt * 16 + lm) * L_TOK]);   // V[token 0][dim]
#pragma unroll
        for (int r = 0; r < 4; r++) oacc[nt][r] = v0;          // p0 = 1
    }
#pragma unroll
    for (int r = 0; r < 4; r++) {
        m_run[r] = __shfl(s0, q4 * 4 + r);
        l_run[r] = 1.f;
    }

    for (int t0 = lo; t0 < kend; t0 += 64) {
        // ---- QK^T: key token for element (nt, ·) at lane (lm,q4) is j = t0 + nt*16 + lm
        f32x4 sacc[4];
#pragma unroll
        for (int nt = 0; nt < 4; nt++) sacc[nt] = (f32x4){0.f, 0.f, 0.f, 0.f};
#pragma unroll
        for (int nt = 0; nt < 4; nt++) {
            int j = t0 + nt * 16 + lm;
            int jc = j > L_TOK - 1 ? L_TOK - 1 : j;
            const ushort_t* Kp = K + (size_t)jc * 512 + h * 64 + q4 * 8;
            bf16x8 bK0 = *reinterpret_cast<const bf16x8*>(Kp);
            bf16x8 bK1 = *reinterpret_cast<const bf16x8*>(Kp + 32);
            sacc[nt] = __builtin_amdgcn_mfma_f32_16x16x32_bf16(aQ0, bK0, sacc[nt], 0, 0, 0);
            sacc[nt] = __builtin_amdgcn_mfma_f32_16x16x32_bf16(aQ1, bK1, sacc[nt], 0, 0, 0);
        }

        // ---- scale + mask: valid(q=iq0+r, j) = sq[r] <= j < iq0+r  (implies j < kend)
#pragma unroll
        for (int nt = 0; nt < 4; nt++) {
            int j = t0 + nt * 16 + lm;
#pragma unroll
            for (int r = 0; r < 4; r++) {
                float s = sacc[nt][r] * 0.125f;
                bool val = (sq[r] <= j) && (j < iq0 + r);
                sacc[nt][r] = val ? s : -INFINITY;
            }
        }

        // ---- online softmax (m_run finite from token-0 init; all-masked rows are no-ops)
        float mnew[4], alpha[4];
#pragma unroll
        for (int r = 0; r < 4; r++) {
            float mx = fmaxf(fmaxf(sacc[0][r], sacc[1][r]), fmaxf(sacc[2][r], sacc[3][r]));
            mx = fmaxf(mx, __shfl_xor(mx, 1));
            mx = fmaxf(mx, __shfl_xor(mx, 2));
            mx = fmaxf(mx, __shfl_xor(mx, 4));
            mx = fmaxf(mx, __shfl_xor(mx, 8));
            float mn = fmaxf(m_run[r], mx);
            mnew[r] = mn;
            alpha[r] = __expf(m_run[r] - mn);
        }

#pragma unroll
        for (int r = 0; r < 4; r++) {
            float rs = 0.f;
#pragma unroll
            for (int nt = 0; nt < 4; nt++) {
                float p = __expf(sacc[nt][r] - mnew[r]);   // masked -> 0
                rs += p;
                Ps[(q4 * 4 + r) * 72 + nt * 16 + lm] = f2b(p);
            }
            rs += __shfl_xor(rs, 1);
            rs += __shfl_xor(rs, 2);
            rs += __shfl_xor(rs, 4);
            rs += __shfl_xor(rs, 8);
            l_run[r] = l_run[r] * alpha[r] + rs;
            m_run[r] = mnew[r];
        }
#pragma unroll
        for (int nt = 0; nt < 4; nt++)
#pragma unroll
            for (int r = 0; r < 4; r++) oacc[nt][r] *= alpha[r];

        // ---- PV: P A-frags (k-slot = q4*8+j -> token t0+q4*8+j), V^T B-frags from global
        bf16x8 aP0 = *reinterpret_cast<const bf16x8*>(&Ps[lm * 72 + q4 * 8]);
        bf16x8 aP1 = *reinterpret_cast<const bf16x8*>(&Ps[lm * 72 + 32 + q4 * 8]);
#pragma unroll
        for (int nt = 0; nt < 4; nt++) {
            const ushort_t* vp = VTh + (size_t)(nt * 16 + lm) * L_TOK + t0;
            bf16x8 bV0 = *reinterpret_cast<const bf16x8*>(vp + q4 * 8);
            bf16x8 bV1 = *reinterpret_cast<const bf16x8*>(vp + 32 + q4 * 8);
            oacc[nt] = __builtin_amdgcn_mfma_f32_16x16x32_bf16(aP0, bV0, oacc[nt], 0, 0, 0);
            oacc[nt] = __builtin_amdgcn_mfma_f32_16x16x32_bf16(aP1, bV1, oacc[nt], 0, 0, 0);
        }
    }

    // ---- epilogue: O[query][h*64+dim] = oacc / l  (C-layout)
#pragma unroll
    for (int r = 0; r < 4; r++) {
        float inv = (l_run[r] > 0.f) ? (1.f / l_run[r]) : 0.f;
#pragma unroll
        for (int nt = 0; nt < 4; nt++)
            O[(size_t)(iq0 + r) * 512 + h * 64 + nt * 16 + lm] = f2b(oacc[nt][r] * inv);
    }
}

// ---------------- LayerNorm (one wave per token); RESID adds R; F32OUT selects output format
template<int RESID, int F32OUT>
__global__ __launch_bounds__(256) void ln_kernel(
    const ushort_t* __restrict__ X, const ushort_t* __restrict__ R,
    const float* __restrict__ g, const float* __restrict__ be,
    void* __restrict__ outv)
{
    int tok = blockIdx.x * 4 + (threadIdx.x >> 6);
    int lane = threadIdx.x & 63;
    size_t base = (size_t)tok * 512 + lane * 8;

    float v[8];
    {
        uint4 ux = *reinterpret_cast<const uint4*>(&X[base]);
        uint_t ua[4] = {ux.x, ux.y, ux.z, ux.w};
#pragma unroll
        for (int p = 0; p < 4; p++) {
            v[2 * p] = b2f((ushort_t)(ua[p] & 0xffffu));
            v[2 * p + 1] = b2f((ushort_t)(ua[p] >> 16));
        }
        if (RESID) {
            uint4 ur = *reinterpret_cast<const uint4*>(&R[base]);
            uint_t ub[4] = {ur.x, ur.y, ur.z, ur.w};
#pragma unroll
            for (int p = 0; p < 4; p++) {
                v[2 * p] += b2f((ushort_t)(ub[p] & 0xffffu));
                v[2 * p + 1] += b2f((ushort_t)(ub[p] >> 16));
            }
        }
    }
    float sum = 0.f;
#pragma unroll
    for (int j = 0; j < 8; j++) sum += v[j];
#pragma unroll
    for (int off = 32; off > 0; off >>= 1) sum += __shfl_xor(sum, off);
    float mu = sum * (1.f / 512.f);
    float var = 0.f;
#pragma unroll
    for (int j = 0; j < 8; j++) { float d = v[j] - mu; var += d * d; }
#pragma unroll
    for (int off = 32; off > 0; off >>= 1) var += __shfl_xor(var, off);
    float rstd = rsqrtf(var * (1.f / 512.f) + 1e-5f);

    const float4* gp = reinterpret_cast<const float4*>(g);
    const float4* bp = reinterpret_cast<const float4*>(be);
    float4 g0 = gp[2 * lane], g1 = gp[2 * lane + 1];
    float4 b0 = bp[2 * lane], b1 = bp[2 * lane + 1];
    float gg[8] = {g0.x, g0.y, g0.z, g0.w, g1.x, g1.y, g1.z, g1.w};
    float bb[8] = {b0.x, b0.y, b0.z, b0.w, b1.x, b1.y, b1.z, b1.w};

    float o[8];
#pragma unroll
    for (int j = 0; j < 8; j++) o[j] = (v[j] - mu) * rstd * gg[j] + bb[j];

    if (F32OUT) {
        float* outf = (float*)outv;
        float4 o0 = {o[0], o[1], o[2], o[3]};
        float4 o1 = {o[4], o[5], o[6], o[7]};
        *reinterpret_cast<float4*>(&outf[base]) = o0;
        *reinterpret_cast<float4*>(&outf[base + 4]) = o1;
    } else {
        ushort_t* outb = (ushort_t*)outv;
        uint_t outp[4];
#pragma unroll
        for (int p = 0; p < 4; p++)
            outp[p] = (uint_t)f2b(o[2 * p]) | ((uint_t)f2b(o[2 * p + 1]) << 16);
        uint4 ov; ov.x = outp[0]; ov.y = outp[1]; ov.z = outp[2]; ov.w = outp[3];
        *reinterpret_cast<uint4*>(&outb[base]) = ov;
    }
}

extern "C" void kernel_launch(void* const* d_in, const int* in_sizes, int n_in,
                              void* d_out, int out_size, void* d_ws, size_t ws_size,
                              hipStream_t stream) {
    const int*   idx = (const int*)d_in[0];
    const int*   seq = (const int*)d_in[1];
    const float* Wt  = (const float*)d_in[2];
    const float* bt  = (const float*)d_in[3];
    const float* Wa  = (const float*)d_in[4];
    const float* ba  = (const float*)d_in[5];
    const float* Wm  = (const float*)d_in[6];
    const float* bm  = (const float*)d_in[7];
    const float* sos = (const float*)d_in[8];
    const float* Wq  = (const float*)d_in[9];
    const float* bq  = (const float*)d_in[10];
    const float* Wk  = (const float*)d_in[11];
    const float* bk  = (const float*)d_in[12];
    const float* Wv  = (const float*)d_in[13];
    const float* bv  = (const float*)d_in[14];
    const float* Wo  = (const float*)d_in[15];
    const float* bo  = (const float*)d_in[16];
    const float* W1  = (const float*)d_in[17];
    const float* b1  = (const float*)d_in[18];
    const float* W2  = (const float*)d_in[19];
    const float* b2  = (const float*)d_in[20];
    const float* g1  = (const float*)d_in[21];
    const float* be1 = (const float*)d_in[22];
    const float* g2  = (const float*)d_in[23];
    const float* be2 = (const float*)d_in[24];

    const size_t NB = (size_t)L_TOK * DMODEL;

    int* START = (int*)d_ws;
    ushort_t* WB = (ushort_t*)d_ws + 16384;
    ushort_t* WQc = WB + 0 * WELEM;
    ushort_t* WKc = WB + 1 * WELEM;
    ushort_t* WVc = WB + 2 * WELEM;
    ushort_t* WOc = WB + 3 * WELEM;
    ushort_t* W1c = WB + 4 * WELEM;
    ushort_t* W2c = WB + 5 * WELEM;
    ushort_t* bufs = WB + 6 * WELEM;
    ushort_t* B0 = bufs;            // X / attn-out / next-layer X
    ushort_t* B1 = bufs + 1 * NB;   // Q / O-proj out / FF hidden
    ushort_t* B2 = bufs + 2 * NB;   // K / XA
    ushort_t* B3 = bufs + 3 * NB;   // VT (512x3072) / FF2 out

    prologue_kernel<<<7681, 256, 0, stream>>>(
        Wq, Wk, Wv, Wo, W1, W2, WB,
        idx, Wt, bt, Wa, ba, Wm, bm, sos, B0,
        seq, START);

    for (int layer = 0; layer < 2; layer++) {
        gemm512<0, 1><<<dim3(96, 8, 3), 256, 0, stream>>>(B0, WQc, WKc, WVc, bq, bk, bv, B1, B2, B3);
        attn_mfma<<<384, 256, 0, stream>>>(B1, B2, B3, START, B0);
        gemm512<0, 0><<<dim3(96, 8, 1), 256, 0, stream>>>(B0, WOc, WOc, WOc, bo, bo, bo, B1, B1, B1);
        ln_kernel<0, 0><<<768, 256, 0, stream>>>(B1, B1, g1, be1, B2);          // XA -> B2
        gemm512<1, 0><<<dim3(96, 8, 1), 256, 0, stream>>>(B2, W1c, W1c, W1c, b1, b1, b1, B1, B1, B1);
        gemm512<0, 0><<<dim3(96, 8, 1), 256, 0, stream>>>(B1, W2c, W2c, W2c, b2, b2, b2, B3, B3, B3);
        if (layer == 0)
            ln_kernel<1, 0><<<768, 256, 0, stream>>>(B3, B2, g2, be2, B0);      // bf16 internal
        else
            ln_kernel<1, 1><<<768, 256, 0, stream>>>(B3, B2, g2, be2, d_out);   // fp32 final output
    }
}

// Round 14
// 253.640 us; speedup vs baseline: 1.0804x; 1.0804x over previous
//
#include <hip/hip_runtime.h>

typedef unsigned short ushort_t;
typedef unsigned int uint_t;

#define L_TOK 3072
#define DMODEL 512
#define WELEM 262144   // 512*512

using bf16x8 = __attribute__((ext_vector_type(8))) short;
using f32x4  = __attribute__((ext_vector_type(4))) float;

__device__ __forceinline__ float b2f(ushort_t u) {
    union { uint_t i; float f; } c; c.i = ((uint_t)u) << 16; return c.f;
}
__device__ __forceinline__ ushort_t f2b(float f) {
    union { float f; uint_t i; } c; c.f = f;
    uint_t x = c.i;
    return (ushort_t)((x + 0x7fffu + ((x >> 16) & 1u)) >> 16);  // RNE
}

// ---------------- Fused prologue: blocks [0,1536) convert weights, [1536,7680) embed,
// block 7680 computes start[] scan.
__global__ __launch_bounds__(256) void prologue_kernel(
    const float* __restrict__ Wq, const float* __restrict__ Wk, const float* __restrict__ Wv,
    const float* __restrict__ Wo, const float* __restrict__ W1, const float* __restrict__ W2,
    ushort_t* __restrict__ WB,
    const int* __restrict__ idx,
    const float* __restrict__ Wt, const float* __restrict__ bt,
    const float* __restrict__ Wa, const float* __restrict__ ba,
    const float* __restrict__ Wm, const float* __restrict__ bm,
    const float* __restrict__ sos, ushort_t* __restrict__ X,
    const int* __restrict__ seq, int* __restrict__ start)
{
    __shared__ int sbuf0[256];
    __shared__ int sbuf1[256];
    int bid = blockIdx.x;
    int tid = threadIdx.x;

    if (bid < 1536) {
        int gid = bid * 256 + tid;
        int mat = gid >> 16;
        int off = (gid & 65535) * 4;
        const float* src;
        switch (mat) {
            case 0: src = Wq; break;
            case 1: src = Wk; break;
            case 2: src = Wv; break;
            case 3: src = Wo; break;
            case 4: src = W1; break;
            default: src = W2; break;
        }
        float4 v = *reinterpret_cast<const float4*>(src + off);
        uint2 o;
        o.x = (uint_t)f2b(v.x) | ((uint_t)f2b(v.y) << 16);
        o.y = (uint_t)f2b(v.z) | ((uint_t)f2b(v.w) << 16);
        *reinterpret_cast<uint2*>(&WB[mat * WELEM + off]) = o;
    } else if (bid < 7680) {
        int gid = (bid - 1536) * 256 + tid;    // 3072*512 total
        int tok = gid >> 9;
        int d = gid & 511;
        float val;
        if (tok == 0) {
            val = sos[d];
        } else {
            int id = idx[tok - 1];
            int t = id / 219;            // 73*3
            int a = (id / 3) % 73;
            int m = id % 3;
            val = Wt[d * 15 + t] + bt[d]
                + Wa[d * 73 + a] + ba[d]
                + Wm[d * 3 + m] + bm[d];
        }
        X[gid] = f2b(val);
    } else {
        // start[] scan: inclusive max-scan of boundary(i) over 3072, 12 chunks of 256
        int carry = 0;
        for (int c = 0; c < 12; c++) {
            int i = c * 256 + tid;
            int b;
            if (i <= 1) b = i;
            else b = (seq[i - 1] == 0) ? i : 0;
            sbuf0[tid] = b;
            __syncthreads();
            int* src = sbuf0;
            int* dst = sbuf1;
            for (int off = 1; off < 256; off <<= 1) {
                int v = src[tid];
                if (tid >= off) { int u = src[tid - off]; if (u > v) v = u; }
                dst[tid] = v;
                __syncthreads();
                int* t = src; src = dst; dst = t;
            }
            int val = src[tid] > carry ? src[tid] : carry;
            start[i] = val;
            int tot = src[255] > carry ? src[255] : carry;
            __syncthreads();
            carry = tot;
        }
    }
}

// ---------------- GEMM: C[3072,512] = A@W^T + bias; 32x64 tile, 4 waves, double-buffered
// (R11 version — measured best at 253.5 us total)
template<int RELU>
__global__ __launch_bounds__(256) void gemm512(
    const ushort_t* __restrict__ A,
    const ushort_t* __restrict__ Wp0, const ushort_t* __restrict__ Wp1, const ushort_t* __restrict__ Wp2,
    const float* __restrict__ bp0, const float* __restrict__ bp1, const float* __restrict__ bp2,
    ushort_t* __restrict__ Cp0, ushort_t* __restrict__ Cp1, ushort_t* __restrict__ Cp2)
{
    const ushort_t* W = Wp0; const float* bias = bp0; ushort_t* C = Cp0;
    if (blockIdx.z == 1) { W = Wp1; bias = bp1; C = Cp1; }
    else if (blockIdx.z == 2) { W = Wp2; bias = bp2; C = Cp2; }

    __shared__ ushort_t As[2 * 32 * 72];
    __shared__ ushort_t Bs[2 * 64 * 72];

    const int tid = threadIdx.x;
    const int lane = tid & 63;
    const int w = tid >> 6;
    const int lm = lane & 15;
    const int q4 = lane >> 4;
    const int r0 = (w & 1) * 16;
    const int c0 = (w >> 1) * 32;

    const int m0 = blockIdx.x * 32;
    const int n0 = blockIdx.y * 64;

    const int srow = tid >> 3;
    const int scol = (tid & 7) << 3;
    const ushort_t* Arow = A + (size_t)(m0 + srow) * 512 + scol;
    const ushort_t* Brow0 = W + (size_t)(n0 + srow) * 512 + scol;
    const ushort_t* Brow1 = Brow0 + (size_t)32 * 512;
    const int ldsA = srow * 72 + scol;
    const int ldsB0 = srow * 72 + scol;
    const int ldsB1 = (srow + 32) * 72 + scol;

    f32x4 acc[2];
    acc[0] = (f32x4){0.f, 0.f, 0.f, 0.f};
    acc[1] = (f32x4){0.f, 0.f, 0.f, 0.f};

    uint4 a0 = *reinterpret_cast<const uint4*>(Arow);
    uint4 b0 = *reinterpret_cast<const uint4*>(Brow0);
    uint4 b1 = *reinterpret_cast<const uint4*>(Brow1);
    *reinterpret_cast<uint4*>(&As[ldsA]) = a0;
    *reinterpret_cast<uint4*>(&Bs[ldsB0]) = b0;
    *reinterpret_cast<uint4*>(&Bs[ldsB1]) = b1;
    __syncthreads();

#pragma unroll
    for (int it = 0; it < 8; it++) {
        const int curA = (it & 1) * 2304;
        const int altA = ((it & 1) ^ 1) * 2304;
        const int curB = (it & 1) * 4608;
        const int altB = ((it & 1) ^ 1) * 4608;
        const int nxt = (it + 1) * 64;

        uint4 na, nb0, nb1;
        if (it < 7) {
            na = *reinterpret_cast<const uint4*>(Arow + nxt);
            nb0 = *reinterpret_cast<const uint4*>(Brow0 + nxt);
            nb1 = *reinterpret_cast<const uint4*>(Brow1 + nxt);
        }

#pragma unroll
        for (int kk = 0; kk < 64; kk += 32) {
            bf16x8 af = *reinterpret_cast<const bf16x8*>(&As[curA + (r0 + lm) * 72 + kk + q4 * 8]);
#pragma unroll
            for (int nt = 0; nt < 2; nt++) {
                bf16x8 bf = *reinterpret_cast<const bf16x8*>(&Bs[curB + (c0 + nt * 16 + lm) * 72 + kk + q4 * 8]);
                acc[nt] = __builtin_amdgcn_mfma_f32_16x16x32_bf16(af, bf, acc[nt], 0, 0, 0);
            }
        }

        if (it < 7) {
            *reinterpret_cast<uint4*>(&As[altA + ldsA]) = na;
            *reinterpret_cast<uint4*>(&Bs[altB + ldsB0]) = nb0;
            *reinterpret_cast<uint4*>(&Bs[altB + ldsB1]) = nb1;
            __syncthreads();
        }
    }

#pragma unroll
    for (int nt = 0; nt < 2; nt++) {
        int col = n0 + c0 + nt * 16 + lm;
        float bv = bias[col];
#pragma unroll
        for (int r = 0; r < 4; r++) {
            int row = m0 + r0 + q4 * 4 + r;
            float v = acc[nt][r] + bv;
            if (RELU) v = (v > 0.f) ? v : 0.01f * v;
            C[(size_t)row * 512 + col] = f2b(v);
        }
    }
}

// ---------------- MFMA flash attention (round-9 version — part of the 253.5 us config)
__global__ __launch_bounds__(256) void attn_mfma(
    const ushort_t* __restrict__ Q, const ushort_t* __restrict__ K,
    const ushort_t* __restrict__ V, const int* __restrict__ START,
    ushort_t* __restrict__ O)
{
    __shared__ ushort_t VtS[4][64 * 72];   // V^T [dim][key], per wave
    __shared__ ushort_t PsS[4][16 * 72];   // P [query][key], per wave

    int w = threadIdx.x >> 6;
    int lane = threadIdx.x & 63;
    ushort_t* Vt = VtS[w];
    ushort_t* Ps = PsS[w];

    int gw = blockIdx.x * 4 + w;          // 1536 units
    int tile = 191 - (gw >> 3);           // reverse: long-range tiles first (LPT)
    int h = gw & 7;
    int i0 = tile * 16;
    int lm = lane & 15;
    int q4 = lane >> 4;

    int iq0 = i0 + q4 * 4;
    int sq[4];
#pragma unroll
    for (int r = 0; r < 4; r++) sq[r] = START[iq0 + r];

    int lo = START[i0]; if (lo < 1) lo = 1;
    int nk = i0 + 16 - lo;

    const ushort_t* Qp = Q + (size_t)(i0 + lm) * 512 + h * 64 + q4 * 8;
    bf16x8 aQ0 = *reinterpret_cast<const bf16x8*>(Qp);
    bf16x8 aQ1 = *reinterpret_cast<const bf16x8*>(Qp + 32);

    float m_run[4], l_run[4];
    f32x4 oacc[4];
#pragma unroll
    for (int r = 0; r < 4; r++) { m_run[r] = -INFINITY; l_run[r] = 0.f; }
#pragma unroll
    for (int nt = 0; nt < 4; nt++) oacc[nt] = (f32x4){0.f, 0.f, 0.f, 0.f};

    for (int t0 = 0; t0 < nk; t0 += 64) {
        int tv = t0 + lane;
        int jv = (tv == 0) ? 0 : (lo + tv - 1);
        if (jv > L_TOK - 1) jv = L_TOK - 1;
        const uint4* vp = reinterpret_cast<const uint4*>(&V[(size_t)jv * 512 + h * 64]);
        uint4 vr[8];
#pragma unroll
        for (int c = 0; c < 8; c++) vr[c] = vp[c];

        int jn[4];
#pragma unroll
        for (int nt = 0; nt < 4; nt++) {
            int t = t0 + nt * 16 + lm;
            jn[nt] = (t == 0) ? 0 : (lo + t - 1);
        }
        f32x4 sacc[4];
#pragma unroll
        for (int nt = 0; nt < 4; nt++) sacc[nt] = (f32x4){0.f, 0.f, 0.f, 0.f};
#pragma unroll
        for (int nt = 0; nt < 4; nt++) {
            int jc = jn[nt] > L_TOK - 1 ? L_TOK - 1 : jn[nt];
            const ushort_t* Kp = K + (size_t)jc * 512 + h * 64 + q4 * 8;
            bf16x8 bK0 = *reinterpret_cast<const bf16x8*>(Kp);
            bf16x8 bK1 = *reinterpret_cast<const bf16x8*>(Kp + 32);
            sacc[nt] = __builtin_amdgcn_mfma_f32_16x16x32_bf16(aQ0, bK0, sacc[nt], 0, 0, 0);
            sacc[nt] = __builtin_amdgcn_mfma_f32_16x16x32_bf16(aQ1, bK1, sacc[nt], 0, 0, 0);
        }

#pragma unroll
        for (int c = 0; c < 8; c++) {
            uint_t ww[4] = {vr[c].x, vr[c].y, vr[c].z, vr[c].w};
#pragma unroll
            for (int e = 0; e < 4; e++) {
                int d0 = c * 8 + e * 2;
                Vt[d0 * 72 + lane] = (ushort_t)(ww[e] & 0xffffu);
                Vt[(d0 + 1) * 72 + lane] = (ushort_t)(ww[e] >> 16);
            }
        }

#pragma unroll
        for (int nt = 0; nt < 4; nt++) {
            int jju = jn[nt];
#pragma unroll
            for (int r = 0; r < 4; r++) {
                float s = sacc[nt][r] * 0.125f;
                bool val = (jju == 0) || (sq[r] <= jju && jju < iq0 + r);
                sacc[nt][r] = val ? s : -INFINITY;
            }
        }

        float mnew[4], alpha[4];
#pragma unroll
        for (int r = 0; r < 4; r++) {
            float mx = fmaxf(fmaxf(sacc[0][r], sacc[1][r]), fmaxf(sacc[2][r], sacc[3][r]));
            mx = fmaxf(mx, __shfl_xor(mx, 1));
            mx = fmaxf(mx, __shfl_xor(mx, 2));
            mx = fmaxf(mx, __shfl_xor(mx, 4));
            mx = fmaxf(mx, __shfl_xor(mx, 8));
            float mn = fmaxf(m_run[r], mx);
            mnew[r] = mn;
            alpha[r] = __expf(m_run[r] - mn);
        }

#pragma unroll
        for (int r = 0; r < 4; r++) {
            float rs = 0.f;
#pragma unroll
            for (int nt = 0; nt < 4; nt++) {
                float p = __expf(sacc[nt][r] - mnew[r]);
                rs += p;
                Ps[(q4 * 4 + r) * 72 + nt * 16 + lm] = f2b(p);
            }
            rs += __shfl_xor(rs, 1);
            rs += __shfl_xor(rs, 2);
            rs += __shfl_xor(rs, 4);
            rs += __shfl_xor(rs, 8);
            l_run[r] = l_run[r] * alpha[r] + rs;
            m_run[r] = mnew[r];
        }
#pragma unroll
        for (int nt = 0; nt < 4; nt++)
#pragma unroll
            for (int r = 0; r < 4; r++) oacc[nt][r] *= alpha[r];

        bf16x8 aP0 = *reinterpret_cast<const bf16x8*>(&Ps[lm * 72 + q4 * 8]);
        bf16x8 aP1 = *reinterpret_cast<const bf16x8*>(&Ps[lm * 72 + 32 + q4 * 8]);
#pragma unroll
        for (int nt = 0; nt < 4; nt++) {
            bf16x8 bV0 = *reinterpret_cast<const bf16x8*>(&Vt[(nt * 16 + lm) * 72 + q4 * 8]);
            bf16x8 bV1 = *reinterpret_cast<const bf16x8*>(&Vt[(nt * 16 + lm) * 72 + 32 + q4 * 8]);
            oacc[nt] = __builtin_amdgcn_mfma_f32_16x16x32_bf16(aP0, bV0, oacc[nt], 0, 0, 0);
            oacc[nt] = __builtin_amdgcn_mfma_f32_16x16x32_bf16(aP1, bV1, oacc[nt], 0, 0, 0);
        }
    }

#pragma unroll
    for (int r = 0; r < 4; r++) {
        float inv = (l_run[r] > 0.f) ? (1.f / l_run[r]) : 0.f;
#pragma unroll
        for (int nt = 0; nt < 4; nt++)
            O[(size_t)(iq0 + r) * 512 + h * 64 + nt * 16 + lm] = f2b(oacc[nt][r] * inv);
    }
}

// ---------------- LayerNorm (one wave per token); RESID adds R; F32OUT selects output format
template<int RESID, int F32OUT>
__global__ __launch_bounds__(256) void ln_kernel(
    const ushort_t* __restrict__ X, const ushort_t* __restrict__ R,
    const float* __restrict__ g, const float* __restrict__ be,
    void* __restrict__ outv)
{
    int tok = blockIdx.x * 4 + (threadIdx.x >> 6);
    int lane = threadIdx.x & 63;
    size_t base = (size_t)tok * 512 + lane * 8;

    float v[8];
    {
        uint4 ux = *reinterpret_cast<const uint4*>(&X[base]);
        uint_t ua[4] = {ux.x, ux.y, ux.z, ux.w};
#pragma unroll
        for (int p = 0; p < 4; p++) {
            v[2 * p] = b2f((ushort_t)(ua[p] & 0xffffu));
            v[2 * p + 1] = b2f((ushort_t)(ua[p] >> 16));
        }
        if (RESID) {
            uint4 ur = *reinterpret_cast<const uint4*>(&R[base]);
            uint_t ub[4] = {ur.x, ur.y, ur.z, ur.w};
#pragma unroll
            for (int p = 0; p < 4; p++) {
                v[2 * p] += b2f((ushort_t)(ub[p] & 0xffffu));
                v[2 * p + 1] += b2f((ushort_t)(ub[p] >> 16));
            }
        }
    }
    float sum = 0.f;
#pragma unroll
    for (int j = 0; j < 8; j++) sum += v[j];
#pragma unroll
    for (int off = 32; off > 0; off >>= 1) sum += __shfl_xor(sum, off);
    float mu = sum * (1.f / 512.f);
    float var = 0.f;
#pragma unroll
    for (int j = 0; j < 8; j++) { float d = v[j] - mu; var += d * d; }
#pragma unroll
    for (int off = 32; off > 0; off >>= 1) var += __shfl_xor(var, off);
    float rstd = rsqrtf(var * (1.f / 512.f) + 1e-5f);

    const float4* gp = reinterpret_cast<const float4*>(g);
    const float4* bp = reinterpret_cast<const float4*>(be);
    float4 g0 = gp[2 * lane], g1 = gp[2 * lane + 1];
    float4 b0 = bp[2 * lane], b1 = bp[2 * lane + 1];
    float gg[8] = {g0.x, g0.y, g0.z, g0.w, g1.x, g1.y, g1.z, g1.w};
    float bb[8] = {b0.x, b0.y, b0.z, b0.w, b1.x, b1.y, b1.z, b1.w};

    float o[8];
#pragma unroll
    for (int j = 0; j < 8; j++) o[j] = (v[j] - mu) * rstd * gg[j] + bb[j];

    if (F32OUT) {
        float* outf = (float*)outv;
        float4 o0 = {o[0], o[1], o[2], o[3]};
        float4 o1 = {o[4], o[5], o[6], o[7]};
        *reinterpret_cast<float4*>(&outf[base]) = o0;
        *reinterpret_cast<float4*>(&outf[base + 4]) = o1;
    } else {
        ushort_t* outb = (ushort_t*)outv;
        uint_t outp[4];
#pragma unroll
        for (int p = 0; p < 4; p++)
            outp[p] = (uint_t)f2b(o[2 * p]) | ((uint_t)f2b(o[2 * p + 1]) << 16);
        uint4 ov; ov.x = outp[0]; ov.y = outp[1]; ov.z = outp[2]; ov.w = outp[3];
        *reinterpret_cast<uint4*>(&outb[base]) = ov;
    }
}

extern "C" void kernel_launch(void* const* d_in, const int* in_sizes, int n_in,
                              void* d_out, int out_size, void* d_ws, size_t ws_size,
                              hipStream_t stream) {
    const int*   idx = (const int*)d_in[0];
    const int*   seq = (const int*)d_in[1];
    const float* Wt  = (const float*)d_in[2];
    const float* bt  = (const float*)d_in[3];
    const float* Wa  = (const float*)d_in[4];
    const float* ba  = (const float*)d_in[5];
    const float* Wm  = (const float*)d_in[6];
    const float* bm  = (const float*)d_in[7];
    const float* sos = (const float*)d_in[8];
    const float* Wq  = (const float*)d_in[9];
    const float* bq  = (const float*)d_in[10];
    const float* Wk  = (const float*)d_in[11];
    const float* bk  = (const float*)d_in[12];
    const float* Wv  = (const float*)d_in[13];
    const float* bv  = (const float*)d_in[14];
    const float* Wo  = (const float*)d_in[15];
    const float* bo  = (const float*)d_in[16];
    const float* W1  = (const float*)d_in[17];
    const float* b1  = (const float*)d_in[18];
    const float* W2  = (const float*)d_in[19];
    const float* b2  = (const float*)d_in[20];
    const float* g1  = (const float*)d_in[21];
    const float* be1 = (const float*)d_in[22];
    const float* g2  = (const float*)d_in[23];
    const float* be2 = (const float*)d_in[24];

    const size_t NB = (size_t)L_TOK * DMODEL;

    int* START = (int*)d_ws;
    ushort_t* WB = (ushort_t*)d_ws + 16384;
    ushort_t* WQc = WB + 0 * WELEM;
    ushort_t* WKc = WB + 1 * WELEM;
    ushort_t* WVc = WB + 2 * WELEM;
    ushort_t* WOc = WB + 3 * WELEM;
    ushort_t* W1c = WB + 4 * WELEM;
    ushort_t* W2c = WB + 5 * WELEM;
    ushort_t* bufs = WB + 6 * WELEM;
    ushort_t* B0 = bufs;            // X / attn-out / next-layer X
    ushort_t* B1 = bufs + 1 * NB;   // Q / O-proj out / FF hidden
    ushort_t* B2 = bufs + 2 * NB;   // K / XA
    ushort_t* B3 = bufs + 3 * NB;   // V / FF2 out

    prologue_kernel<<<7681, 256, 0, stream>>>(
        Wq, Wk, Wv, Wo, W1, W2, WB,
        idx, Wt, bt, Wa, ba, Wm, bm, sos, B0,
        seq, START);

    for (int layer = 0; layer < 2; layer++) {
        gemm512<0><<<dim3(96, 8, 3), 256, 0, stream>>>(B0, WQc, WKc, WVc, bq, bk, bv, B1, B2, B3);
        attn_mfma<<<384, 256, 0, stream>>>(B1, B2, B3, START, B0);
        gemm512<0><<<dim3(96, 8, 1), 256, 0, stream>>>(B0, WOc, WOc, WOc, bo, bo, bo, B1, B1, B1);
        ln_kernel<0, 0><<<768, 256, 0, stream>>>(B1, B1, g1, be1, B2);          // XA -> B2
        gemm512<1><<<dim3(96, 8, 1), 256, 0, stream>>>(B2, W1c, W1c, W1c, b1, b1, b1, B1, B1, B1);
        gemm512<0><<<dim3(96, 8, 1), 256, 0, stream>>>(B1, W2c, W2c, W2c, b2, b2, b2, B3, B3, B3);
        if (layer == 0)
            ln_kernel<1, 0><<<768, 256, 0, stream>>>(B3, B2, g2, be2, B0);      // bf16 internal
        else
            ln_kernel<1, 1><<<768, 256, 0, stream>>>(B3, B2, g2, be2, d_out);   // fp32 final output
    }
}